// Round 4
// baseline (461.271 us; speedup 1.0000x reference)
//
#include <hip/hip_runtime.h>

#define T_TOK 4096
#define DIN   1024
#define DOUT  1024
#define NEXP  8
#define HDIM  4096
#define RCAP  10240      // 8192 rows, each expert padded to 256
#define MT256 40
#define MT128 80

typedef float f32x4 __attribute__((ext_vector_type(4)));
typedef short bf16x8 __attribute__((ext_vector_type(8)));
typedef unsigned short u16x4 __attribute__((ext_vector_type(4)));

__device__ __forceinline__ float bf2f(unsigned short u) {
    union { unsigned int i; float f; } v; v.i = ((unsigned int)u) << 16; return v.f;
}
__device__ __forceinline__ unsigned short f2bf(float f) {
    union { unsigned int i; float f; } v; v.f = f;
    unsigned int r = v.i + 0x7FFFu + ((v.i >> 16) & 1u);
    return (unsigned short)(r >> 16);
}

__global__ void init_kernel(int* cnt) {
    if (threadIdx.x < NEXP) cnt[threadIdx.x] = 0;
}

// One wave per token: fp64 gating dots, softplus, top-2, softmax, routing.
__global__ __launch_bounds__(64) void gating_kernel(
    const float* __restrict__ x, const float* __restrict__ noise,
    const float* __restrict__ gw, const float* __restrict__ gb,
    const float* __restrict__ nw, const float* __restrict__ nb,
    float* __restrict__ wout, int* __restrict__ cnt,
    int* __restrict__ tok_e, int* __restrict__ tok_slot, float* __restrict__ tok_p)
{
    int t = blockIdx.x;
    int lane = threadIdx.x;
    const float* xr = x + (size_t)t * DIN;
    double ag[NEXP], an[NEXP];
#pragma unroll
    for (int e = 0; e < NEXP; ++e) { ag[e] = 0.0; an[e] = 0.0; }
    for (int d = lane; d < DIN; d += 64) {
        double xv = (double)xr[d];
        const f32x4* g4 = (const f32x4*)(gw + (size_t)d * NEXP);
        const f32x4* n4 = (const f32x4*)(nw + (size_t)d * NEXP);
        f32x4 ga = g4[0], gbv = g4[1], na = n4[0], nbv = n4[1];
#pragma unroll
        for (int j = 0; j < 4; ++j) {
            ag[j]     += xv * (double)ga[j];
            ag[4 + j] += xv * (double)gbv[j];
            an[j]     += xv * (double)na[j];
            an[4 + j] += xv * (double)nbv[j];
        }
    }
#pragma unroll
    for (int e = 0; e < NEXP; ++e) {
        double g = ag[e], n = an[e];
#pragma unroll
        for (int m = 32; m > 0; m >>= 1) { g += __shfl_xor(g, m); n += __shfl_xor(n, m); }
        ag[e] = g; an[e] = n;
    }
    double lg[NEXP];
#pragma unroll
    for (int e = 0; e < NEXP; ++e) {
        double z = an[e] + (double)nb[e];
        double sp = fmax(z, 0.0) + log1p(exp(-fabs(z)));
        lg[e] = ag[e] + (double)gb[e] + (double)noise[(size_t)t * NEXP + e] * sp;
    }
    int i0 = 0; double v0 = lg[0];
#pragma unroll
    for (int e = 1; e < NEXP; ++e) if (lg[e] > v0) { v0 = lg[e]; i0 = e; }
    int i1 = -1; double v1 = -1.0e300;
#pragma unroll
    for (int e = 0; e < NEXP; ++e) if (e != i0 && lg[e] > v1) { v1 = lg[e]; i1 = e; }
    double d1 = exp(v1 - v0);
    float p0 = (float)(1.0 / (1.0 + d1));
    float p1 = (float)(d1 / (1.0 + d1));
    if (lane < NEXP) {
        float wv = (lane == i0) ? p0 : ((lane == i1) ? p1 : 0.0f);
        wout[(size_t)t * NEXP + lane] = wv;
    }
    if (lane == 0) {
        int s0 = atomicAdd(&cnt[i0], 1);
        int s1 = atomicAdd(&cnt[i1], 1);
        tok_e[2 * t] = i0;     tok_e[2 * t + 1] = i1;
        tok_slot[2 * t] = s0;  tok_slot[2 * t + 1] = s1;
        tok_p[2 * t] = p0;     tok_p[2 * t + 1] = p1;
    }
}

// 256-row-aligned per-expert offsets + 256-tile map (GEMM1) + 128-tile map (GEMM2).
__global__ void prefix_kernel(const int* __restrict__ cnt, int* __restrict__ poff,
                              int* __restrict__ t2e256, int* __restrict__ trow256,
                              int* __restrict__ t2e128, int* __restrict__ trow128)
{
    if (threadIdx.x != 0 || blockIdx.x != 0) return;
    int base = 0, a = 0, b = 0;
    for (int e = 0; e < NEXP; ++e) {
        poff[e] = base;
        int c = cnt[e];
        int nt = (c + 255) >> 8;
        for (int i = 0; i < nt; ++i)     { t2e256[a] = e; trow256[a] = base + (i << 8); ++a; }
        for (int i = 0; i < 2 * nt; ++i) { t2e128[b] = e; trow128[b] = base + (i << 7); ++b; }
        base += nt << 8;
    }
    for (; a < MT256; ++a) { t2e256[a] = -1; trow256[a] = 0; }
    for (; b < MT128; ++b) { t2e128[b] = -1; trow128[b] = 0; }
}

// Copy token row t (fp32) to its expert slot as bf16.
__global__ __launch_bounds__(256) void gather_kernel(
    const float* __restrict__ x, const int* __restrict__ tok_e,
    const int* __restrict__ tok_slot, const int* __restrict__ poff,
    unsigned short* __restrict__ Xg)
{
    int b = blockIdx.x;
    int t = b >> 1, k = b & 1;
    int e = tok_e[2 * t + k];
    int row = poff[e] + tok_slot[2 * t + k];
    int c = threadIdx.x << 2;
    f32x4 v = *(const f32x4*)(x + (size_t)t * DIN + c);
    u16x4 o;
#pragma unroll
    for (int j = 0; j < 4; ++j) o[j] = f2bf(v[j]);
    *(u16x4*)(Xg + (size_t)row * DIN + c) = o;
}

// Transpose+convert: W [E][K][N] fp32 -> Wt [E][N][K] bf16 (64x64 LDS tiles).
__global__ __launch_bounds__(256) void convw_kernel(
    const float* __restrict__ W, unsigned short* __restrict__ Wt, int K, int N)
{
    __shared__ float tile[64][65];
    int e = blockIdx.x;
    int k0 = blockIdx.y << 6;
    int n0 = blockIdx.z << 6;
    int tid = threadIdx.x;
    const float* src = W + ((size_t)e * K + k0) * N + n0;
    int r = tid >> 4, c4 = (tid & 15) << 2;
#pragma unroll
    for (int i = 0; i < 4; ++i) {
        f32x4 v = *(const f32x4*)(src + (size_t)(r + (i << 4)) * N + c4);
        *(f32x4*)(&tile[r + (i << 4)][c4]) = v;
    }
    __syncthreads();
    unsigned short* dst = Wt + ((size_t)e * N + n0) * K + k0;
    int n = tid >> 2, kq = (tid & 3) << 4;
#pragma unroll
    for (int j = 0; j < 4; ++j) {
        int kk = kq + (j << 2);
        u16x4 o;
#pragma unroll
        for (int q = 0; q < 4; ++q) o[q] = f2bf(tile[kk + q][n]);
        *(u16x4*)(dst + (size_t)n * K + kk) = o;
    }
}

// GEMM1: 256x256 tile, BK=32, 8 waves (2Mx4N, wave tile 128x64), 3-buffer LDS
// ring, counted vmcnt, raw s_barrier, setprio around MFMA, both-sides slot
// swizzle, XCD-chunked n-fastest order. A=Xg[cap][1024], B=W1t[E][4096][1024].
// vmcnt ledger (per wave, 4 load-instrs per tile):
//   prologue: issue tile0(4)+tile1(4)=8 -> vmcnt(4) retires tile0 exactly.
//   iter t: +2 (A of t+2) in ph0, +2 (B of t+2) in ph1 -> vmcnt(4) retires t+1.
//   tail (t>=NKT-2): vmcnt(0) drains.
__global__ __launch_bounds__(512, 2) void gemm1_256_kernel(
    const unsigned short* __restrict__ A,
    const unsigned short* __restrict__ Bt,
    unsigned short* __restrict__ C,          // H [cap][4096]
    const float* __restrict__ bias,          // b1 [E][4096]
    const int* __restrict__ t2e, const int* __restrict__ trow)
{
    const int K = 1024, N = 4096, NKT = 32;
    int cpx = gridDim.x >> 3;
    int wg = ((blockIdx.x & 7) * cpx) + (blockIdx.x >> 3);
    int tileid = wg >> 4;
    int nb = wg & 15;
    int e = t2e[tileid];
    if (e < 0) return;
    int row0 = trow[tileid];
    int n0 = nb << 8;

    __shared__ __align__(16) unsigned short lds[3 * 16384];   // 3 x (A 16KB + B 16KB)

    int tid = threadIdx.x;
    int lane = tid & 63;
    int wv = tid >> 6;
    int wr = wv >> 2;        // 0..1  -> rows wr*128..+127
    int wc = wv & 3;         // 0..3  -> cols wc*64..+63

    const unsigned short* Ab = A + (size_t)row0 * K;
    const unsigned short* Bb = Bt + ((size_t)e * N + n0) * K;

    f32x4 acc[8][4] = {};

    // read-side swizzle: slot = (lane>>4) ^ ((row>>1)&3); row base mult of 16
    int hr = lane & 15;
    int slotR = (((lane >> 4) ^ ((hr >> 1) & 3)) << 3);   // elem offset in 32-elem row
    // stage-side: thread covers row sr of 128-row part, 16B slot (tid&3), pre-swizzled source
    int sr = tid >> 2;
    int scol = (((tid & 3) ^ ((sr >> 1) & 3)) << 3);

    // prologue: stage tiles 0 and 1
#pragma unroll
    for (int t = 0; t < 2; ++t) {
        int kb = t << 5;
        unsigned short* ldst = &lds[t * 16384];
#pragma unroll
        for (int w = 0; w < 2; ++w) {
            const unsigned short* ga = Ab + (size_t)((w << 7) + sr) * K + kb + scol;
            const unsigned short* gb = Bb + (size_t)((w << 7) + sr) * K + kb + scol;
            __builtin_amdgcn_global_load_lds(
                (const __attribute__((address_space(1))) void*)ga,
                (__attribute__((address_space(3))) void*)(ldst + (w << 12) + (wv << 9)), 16, 0, 0);
            __builtin_amdgcn_global_load_lds(
                (const __attribute__((address_space(1))) void*)gb,
                (__attribute__((address_space(3))) void*)(ldst + 8192 + (w << 12) + (wv << 9)), 16, 0, 0);
        }
    }
    asm volatile("s_waitcnt vmcnt(4)" ::: "memory");   // tile 0 resident; tile 1 in flight
    asm volatile("s_barrier" ::: "memory");

    int bt = 0, bs = 2;
    for (int t = 0; t < NKT; ++t) {
        const unsigned short* lA = &lds[bt * 16384];
        const unsigned short* lB = lA + 8192;
        unsigned short* ldst = &lds[bs * 16384];
        bool stage = (t + 2) < NKT;
        int kb2 = (t + 2) << 5;

        // ---- phase 0: C-quadrant m-half 0 ----
        bf16x8 af[4], bv[4];
#pragma unroll
        for (int mf = 0; mf < 4; ++mf)
            af[mf] = *(const bf16x8*)&lA[(((wr << 7) + (mf << 4) + hr) << 5) + slotR];
#pragma unroll
        for (int nf = 0; nf < 4; ++nf)
            bv[nf] = *(const bf16x8*)&lB[(((wc << 6) + (nf << 4) + hr) << 5) + slotR];
        if (stage) {
#pragma unroll
            for (int w = 0; w < 2; ++w) {
                const unsigned short* ga = Ab + (size_t)((w << 7) + sr) * K + kb2 + scol;
                __builtin_amdgcn_global_load_lds(
                    (const __attribute__((address_space(1))) void*)ga,
                    (__attribute__((address_space(3))) void*)(ldst + (w << 12) + (wv << 9)), 16, 0, 0);
            }
        }
        asm volatile("s_barrier" ::: "memory");
        __builtin_amdgcn_s_setprio(1);
#pragma unroll
        for (int mf = 0; mf < 4; ++mf)
#pragma unroll
            for (int nf = 0; nf < 4; ++nf)
                acc[mf][nf] = __builtin_amdgcn_mfma_f32_16x16x32_bf16(af[mf], bv[nf], acc[mf][nf], 0, 0, 0);
        __builtin_amdgcn_s_setprio(0);
        asm volatile("s_barrier" ::: "memory");

        // ---- phase 1: C-quadrant m-half 1 (reuse bv) ----
#pragma unroll
        for (int mf = 0; mf < 4; ++mf)
            af[mf] = *(const bf16x8*)&lA[(((wr << 7) + ((mf + 4) << 4) + hr) << 5) + slotR];
        if (stage) {
#pragma unroll
            for (int w = 0; w < 2; ++w) {
                const unsigned short* gb = Bb + (size_t)((w << 7) + sr) * K + kb2 + scol;
                __builtin_amdgcn_global_load_lds(
                    (const __attribute__((address_space(1))) void*)gb,
                    (__attribute__((address_space(3))) void*)(ldst + 8192 + (w << 12) + (wv << 9)), 16, 0, 0);
            }
            asm volatile("s_waitcnt vmcnt(4)" ::: "memory");   // tile t+1 resident
        } else {
            asm volatile("s_waitcnt vmcnt(0)" ::: "memory");   // tail drain
        }
        asm volatile("s_barrier" ::: "memory");
        __builtin_amdgcn_s_setprio(1);
#pragma unroll
        for (int mf = 0; mf < 4; ++mf)
#pragma unroll
            for (int nf = 0; nf < 4; ++nf)
                acc[mf + 4][nf] = __builtin_amdgcn_mfma_f32_16x16x32_bf16(af[mf], bv[nf], acc[mf + 4][nf], 0, 0, 0);
        __builtin_amdgcn_s_setprio(0);
        asm volatile("s_barrier" ::: "memory");

        bt = (bt == 2) ? 0 : bt + 1;
        bs = (bs == 2) ? 0 : bs + 1;
    }

    // epilogue: bias + ReLU, bf16 store
    int rq = (lane >> 4) << 2;
    int cl = lane & 15;
#pragma unroll
    for (int nf = 0; nf < 4; ++nf) {
        int col = (wc << 6) + (nf << 4) + cl;
        float bvv = bias[(size_t)e * N + n0 + col];
#pragma unroll
        for (int mf = 0; mf < 8; ++mf) {
#pragma unroll
            for (int r = 0; r < 4; ++r) {
                int row = (wr << 7) + (mf << 4) + rq + r;
                float v = acc[mf][nf][r] + bvv;
                v = fmaxf(v, 0.0f);
                C[(size_t)(row0 + row) * N + n0 + col] = f2bf(v);
            }
        }
    }
}

// GEMM2: proven R2 structure (128x128, BK=32, zero-conflict swizzle).
__global__ __launch_bounds__(256, 2) void gemm_bt_kernel(
    const unsigned short* __restrict__ A,
    const unsigned short* __restrict__ Bt,
    unsigned short* __restrict__ C,
    const float* __restrict__ bias,
    const int* __restrict__ t2e, const int* __restrict__ trow,
    int K, int N, int nbshift, int relu)
{
    int nwg = gridDim.x;
    int cpx = nwg >> 3;
    int wg = ((blockIdx.x & 7) * cpx) + (blockIdx.x >> 3);
    int tileid = wg >> nbshift;
    int nb = wg & ((1 << nbshift) - 1);

    int e = t2e[tileid];
    if (e < 0) return;
    int row0 = trow[tileid];
    int n0 = nb << 7;

    __shared__ __align__(16) unsigned short As[128 * 32];
    __shared__ __align__(16) unsigned short Bs[128 * 32];

    int tid = threadIdx.x;
    int lane = tid & 63;
    int wv = tid >> 6;
    int wr = (wv >> 1) << 6;
    int wc = (wv & 1) << 6;

    const unsigned short* Ab = A + (size_t)row0 * K;
    const unsigned short* Bb = Bt + ((size_t)e * N + n0) * K;

    f32x4 acc[4][4] = {};

    int srow = lane >> 2;
    int skc = (((lane & 3) ^ ((lane >> 3) & 3)) << 3);
    int hr = lane & 15;
    int rsw = (lane >> 1) & 3;
    int kfrag = (((lane >> 4) ^ rsw) << 3);

    int nkt = K >> 5;
    for (int kt = 0; kt < nkt; ++kt) {
        __syncthreads();
        int kb = kt << 5;
#pragma unroll
        for (int j = 0; j < 2; ++j) {
            int c = wv + (j << 2);
            int r = (c << 4) + srow;
            const unsigned short* ga = Ab + (size_t)r * K + kb + skc;
            const unsigned short* gbp = Bb + (size_t)r * K + kb + skc;
            __builtin_amdgcn_global_load_lds(
                (const __attribute__((address_space(1))) void*)ga,
                (__attribute__((address_space(3))) void*)(&As[c << 9]), 16, 0, 0);
            __builtin_amdgcn_global_load_lds(
                (const __attribute__((address_space(1))) void*)gbp,
                (__attribute__((address_space(3))) void*)(&Bs[c << 9]), 16, 0, 0);
        }
        __syncthreads();
        bf16x8 af[4], bfv[4];
#pragma unroll
        for (int m = 0; m < 4; ++m)
            af[m] = *(const bf16x8*)(&As[((wr + (m << 4) + hr) << 5) + kfrag]);
#pragma unroll
        for (int n = 0; n < 4; ++n)
            bfv[n] = *(const bf16x8*)(&Bs[((wc + (n << 4) + hr) << 5) + kfrag]);
#pragma unroll
        for (int m = 0; m < 4; ++m)
#pragma unroll
            for (int n = 0; n < 4; ++n)
                acc[m][n] = __builtin_amdgcn_mfma_f32_16x16x32_bf16(af[m], bfv[n], acc[m][n], 0, 0, 0);
    }

    int rq = (lane >> 4) << 2;
    int cl = lane & 15;
#pragma unroll
    for (int n = 0; n < 4; ++n) {
        int col = wc + (n << 4) + cl;
        float bv = bias[(size_t)e * N + n0 + col];
#pragma unroll
        for (int m = 0; m < 4; ++m) {
#pragma unroll
            for (int r = 0; r < 4; ++r) {
                int row = wr + (m << 4) + rq + r;
                float v = acc[m][n][r] + bv;
                if (relu) v = fmaxf(v, 0.0f);
                C[(size_t)(row0 + row) * N + n0 + col] = f2bf(v);
            }
        }
    }
}

// x_out[t] = p0*O[row0] + p1*O[row1]
__global__ __launch_bounds__(256) void combine_kernel(
    const unsigned short* __restrict__ O, const int* __restrict__ tok_e,
    const int* __restrict__ tok_slot, const float* __restrict__ tok_p,
    const int* __restrict__ poff, float* __restrict__ xout)
{
    int t = blockIdx.x;
    int e0 = tok_e[2 * t], e1 = tok_e[2 * t + 1];
    int r0 = poff[e0] + tok_slot[2 * t];
    int r1 = poff[e1] + tok_slot[2 * t + 1];
    float p0 = tok_p[2 * t], p1 = tok_p[2 * t + 1];
    int c = threadIdx.x << 2;
    u16x4 a = *(const u16x4*)(O + (size_t)r0 * DOUT + c);
    u16x4 b = *(const u16x4*)(O + (size_t)r1 * DOUT + c);
    f32x4 r;
#pragma unroll
    for (int j = 0; j < 4; ++j) r[j] = p0 * bf2f(a[j]) + p1 * bf2f(b[j]);
    *(f32x4*)(xout + (size_t)t * DOUT + c) = r;
}

extern "C" void kernel_launch(void* const* d_in, const int* in_sizes, int n_in,
                              void* d_out, int out_size, void* d_ws, size_t ws_size,
                              hipStream_t stream)
{
    const float* x     = (const float*)d_in[0];
    const float* noise = (const float*)d_in[1];
    const float* gw    = (const float*)d_in[2];
    const float* gb    = (const float*)d_in[3];
    const float* nw    = (const float*)d_in[4];
    const float* nb    = (const float*)d_in[5];
    const float* w1    = (const float*)d_in[6];
    const float* b1    = (const float*)d_in[7];
    const float* w2    = (const float*)d_in[8];
    const float* b2    = (const float*)d_in[9];
    float* xout = (float*)d_out;
    float* wout = xout + (size_t)T_TOK * DOUT;

    char* ws = (char*)d_ws;
    int*   cnt      = (int*)(ws + 0);
    int*   poff     = (int*)(ws + 256);
    int*   t2e256   = (int*)(ws + 512);
    int*   trow256  = (int*)(ws + 768);
    int*   t2e128   = (int*)(ws + 1024);
    int*   trow128  = (int*)(ws + 1536);
    int*   tok_e    = (int*)(ws + 2048);
    int*   tok_slot = (int*)(ws + 2048 + 4 * 2 * T_TOK);
    float* tok_p    = (float*)(ws + 2048 + 8 * 2 * T_TOK);
    size_t oXg = 2048 + 12 * 2 * T_TOK;                 // 100352, 256-aligned
    unsigned short* Xg  = (unsigned short*)(ws + oXg);
    unsigned short* O   = Xg;                           // O aliases Xg (dead after GEMM1)
    size_t oH  = oXg + (size_t)RCAP * DIN * 2;
    unsigned short* H   = (unsigned short*)(ws + oH);
    size_t oW1 = oH + (size_t)RCAP * HDIM * 2;
    unsigned short* W1t = (unsigned short*)(ws + oW1);
    size_t oW2 = oW1 + (size_t)NEXP * HDIM * DIN * 2;
    unsigned short* W2t = (unsigned short*)(ws + oW2);
    // total ~239.2 MB

    init_kernel<<<1, 64, 0, stream>>>(cnt);
    gating_kernel<<<T_TOK, 64, 0, stream>>>(x, noise, gw, gb, nw, nb,
                                            wout, cnt, tok_e, tok_slot, tok_p);
    prefix_kernel<<<1, 1, 0, stream>>>(cnt, poff, t2e256, trow256, t2e128, trow128);
    gather_kernel<<<2 * T_TOK, 256, 0, stream>>>(x, tok_e, tok_slot, poff, Xg);
    convw_kernel<<<dim3(NEXP, DIN / 64, HDIM / 64), 256, 0, stream>>>(w1, W1t, DIN, HDIM);
    convw_kernel<<<dim3(NEXP, HDIM / 64, DOUT / 64), 256, 0, stream>>>(w2, W2t, HDIM, DOUT);
    gemm1_256_kernel<<<MT256 * (HDIM / 256), 512, 0, stream>>>(
        Xg, W1t, H, b1, t2e256, trow256);
    gemm_bt_kernel<<<MT128 * (DOUT / 128), 256, 0, stream>>>(
        H, W2t, O, b2, t2e128, trow128, HDIM, DOUT, 3, 0);
    combine_kernel<<<T_TOK, 256, 0, stream>>>(O, tok_e, tok_slot, tok_p, poff, xout);
}